// Round 8
// baseline (87.765 us; speedup 1.0000x reference)
//
#include <hip/hip_runtime.h>

#define S_LEN 2048
#define DMODEL 1024
#define NHEADS 16
#define WIN 256

typedef unsigned short u16;
typedef unsigned int u32;
typedef __attribute__((ext_vector_type(8))) __bf16 bf16x8;
typedef __attribute__((ext_vector_type(4))) float f32x4;
typedef __attribute__((ext_vector_type(8))) u16 u16x8;
typedef __attribute__((ext_vector_type(4))) u16 u16x4;

__device__ __forceinline__ u16 f2bf(float f) {
  u32 u = __builtin_bit_cast(u32, f);
  u += 0x7fffu + ((u >> 16) & 1u);   // round-to-nearest-even
  return (u16)(u >> 16);
}

#define GLDS16(g, l) __builtin_amdgcn_global_load_lds( \
    (const __attribute__((address_space(1))) void*)(g), \
    (__attribute__((address_space(3))) void*)(l), 16, 0, 0)

#define BAR() { asm volatile("" ::: "memory"); __builtin_amdgcn_s_barrier(); asm volatile("" ::: "memory"); }
#define LGKM0() { asm volatile("s_waitcnt lgkmcnt(0)" ::: "memory"); __builtin_amdgcn_sched_barrier(0); }
#define VMCNT(n) asm volatile("s_waitcnt vmcnt(" #n ")" ::: "memory")

// ---------------- fused cast f32 -> bf16 (x + 4 weights, one launch) ----------------
__global__ __launch_bounds__(256) void cast_all(
    const float* __restrict__ x, const float* __restrict__ wq, const float* __restrict__ wk,
    const float* __restrict__ wv, const float* __restrict__ wo,
    u16* __restrict__ xb, u16* __restrict__ wqb, u16* __restrict__ wkb,
    u16* __restrict__ wvb, u16* __restrict__ wob) {
  const int e = (blockIdx.x * 256 + threadIdx.x) * 4;
  const float* src; u16* dst; int off;
  if (e < (1 << 22)) { src = x; dst = xb; off = e; }
  else {
    int r = e - (1 << 22);
    int seg = r >> 20; off = r & ((1 << 20) - 1);
    src = (seg == 0) ? wq : (seg == 1) ? wk : (seg == 2) ? wv : wo;
    dst = (seg == 0) ? wqb : (seg == 1) ? wkb : (seg == 2) ? wvb : wob;
  }
  float4 v = *(const float4*)(src + off);
  u16x4 o = { f2bf(v.x), f2bf(v.y), f2bf(v.z), f2bf(v.w) };
  *(u16x4*)(dst + off) = o;
}

// ---------------- fused QKV GEMM: 256x256 tile, BK=64, 8 waves, 8-phase, T2+T4+T5 ----------------
// C[4096,3072] = A[4096,1024] * [Wq;Wk;Wv]^T + bias -> bf16 Q/K/V.
// Schedule (liveness-audited): quadrants P1(m0-3,n0-1) P2(m0-3,n2-3) P3(m4-7,n2-3) P4(m4-7,n0-1);
// stages P1:B0(u+1) P2:B1(u+1) P4:A0+A1(u+2); one vmcnt(4) gate at P4 (tail: vmcnt(0)).
// T2 swizzle byte^=(row&7)<<4 via inverse-swizzled global src + swizzled ds_read.
__global__ __launch_bounds__(512, 2) void gemm_qkv_8ph(
    const u16* __restrict__ A,
    const u16* __restrict__ Wq, const u16* __restrict__ Wk, const u16* __restrict__ Wv,
    const float* __restrict__ bq, const float* __restrict__ bk, const float* __restrict__ bv,
    u16* __restrict__ Qo, u16* __restrict__ Ko, u16* __restrict__ Vo)
{
  constexpr int K = 1024, NT = 16;

  __shared__ u16 AS[2][2][8192];   // [slot][half][128 rows x 64 k] = 64 KiB
  __shared__ u16 BS[2][2][8192];   // 64 KiB

  const int t = threadIdx.x;
  const int lane = t & 63, lo = lane & 15, hi = lane >> 4;
  const int wid = t >> 6, wm = wid >> 2, wn = wid & 3;
  const int sx = lo & 7;

  const int row0 = blockIdx.x * 256;
  const int by = blockIdx.y;             // 0..11
  const int wsel = by >> 2;
  const int col0 = (by & 3) * 256;
  const u16* Bt = (wsel == 0) ? Wq : (wsel == 1) ? Wk : Wv;
  const float* bias = (wsel == 0) ? bq : (wsel == 1) ? bk : bv;
  u16* C = (wsel == 0) ? Qo : (wsel == 1) ? Ko : Vo;

  const int srow = t >> 3;                       // staging row within 64-row group
  const int kcol = (t & 7) ^ ((t >> 3) & 7);     // inverse-swizzled k16 slot

  auto stageA = [&](int slot, int kt, int h) {
    #pragma unroll
    for (int c = 0; c < 2; ++c)
      GLDS16(A + (size_t)(row0 + h * 128 + c * 64 + srow) * K + kt * 64 + kcol * 8,
             (u16*)AS + slot * 16384 + h * 8192 + c * 4096 + t * 8);
  };
  auto stageB = [&](int slot, int kt, int h) {
    #pragma unroll
    for (int c = 0; c < 2; ++c)
      GLDS16(Bt + (size_t)(col0 + h * 128 + c * 64 + srow) * K + kt * 64 + kcol * 8,
             (u16*)BS + slot * 16384 + h * 8192 + c * 4096 + t * 8);
  };
  auto rdA = [&](int slot, int m, int kk) -> bf16x8 {
    const int byte = ((m * 16 + lo) << 7) + ((((kk << 2) + hi) ^ sx) << 4);
    return *(const bf16x8*)((const char*)AS + slot * 32768 + wm * 16384 + byte);
  };
  auto rdB = [&](int slot, int n, int kk) -> bf16x8 {
    const int byte = (((wn & 1) * 64 + n * 16 + lo) << 7) + ((((kk << 2) + hi) ^ sx) << 4);
    return *(const bf16x8*)((const char*)BS + slot * 32768 + (wn >> 1) * 16384 + byte);
  };

  f32x4 acc[8][4];
  #pragma unroll
  for (int i = 0; i < 8; ++i)
    #pragma unroll
    for (int j = 0; j < 4; ++j) acc[i][j] = (f32x4)0.0f;

  bf16x8 a[4][2], b0[2][2], b1[2][2];

  // prologue: tile0 A+B (8 loads), tile1 A (4 loads); gate tile0
  stageA(0, 0, 0); stageA(0, 0, 1); stageB(0, 0, 0); stageB(0, 0, 1);
  stageA(1, 1, 0); stageA(1, 1, 1);
  VMCNT(4);
  BAR();

  for (int u = 0; u < NT; ++u) {
    const int slot = u & 1;
    const bool nx1 = (u + 1 < NT), nx2 = (u + 2 < NT);

    // ---- P1: reads A m0-3 + B n0-1 (12 ds_read); stage B0(u+1); MFMA Q(m0-3,n0-1) ----
    #pragma unroll
    for (int m = 0; m < 4; ++m) { a[m][0] = rdA(slot, m, 0); a[m][1] = rdA(slot, m, 1); }
    #pragma unroll
    for (int n = 0; n < 2; ++n) { b0[n][0] = rdB(slot, n, 0); b0[n][1] = rdB(slot, n, 1); }
    if (nx1) stageB(slot ^ 1, u + 1, 0);
    BAR();
    LGKM0();
    __builtin_amdgcn_s_setprio(1);
    #pragma unroll
    for (int m = 0; m < 4; ++m)
      #pragma unroll
      for (int n = 0; n < 2; ++n)
        #pragma unroll
        for (int kk = 0; kk < 2; ++kk)
          acc[m][n] = __builtin_amdgcn_mfma_f32_16x16x32_bf16(a[m][kk], b0[n][kk], acc[m][n], 0, 0, 0);
    __builtin_amdgcn_s_setprio(0);
    BAR();

    // ---- P2: reads B n2-3 (4 ds_read); stage B1(u+1); MFMA Q(m0-3,n2-3) ----
    #pragma unroll
    for (int n = 0; n < 2; ++n) { b1[n][0] = rdB(slot, 2 + n, 0); b1[n][1] = rdB(slot, 2 + n, 1); }
    if (nx1) stageB(slot ^ 1, u + 1, 1);
    BAR();
    LGKM0();
    __builtin_amdgcn_s_setprio(1);
    #pragma unroll
    for (int m = 0; m < 4; ++m)
      #pragma unroll
      for (int n = 0; n < 2; ++n)
        #pragma unroll
        for (int kk = 0; kk < 2; ++kk)
          acc[m][2 + n] = __builtin_amdgcn_mfma_f32_16x16x32_bf16(a[m][kk], b1[n][kk], acc[m][2 + n], 0, 0, 0);
    __builtin_amdgcn_s_setprio(0);
    BAR();

    // ---- P3: reads A m4-7 (8 ds_read, overwrites a); MFMA Q(m4-7,n2-3) ----
    #pragma unroll
    for (int m = 0; m < 4; ++m) { a[m][0] = rdA(slot, 4 + m, 0); a[m][1] = rdA(slot, 4 + m, 1); }
    BAR();
    LGKM0();
    __builtin_amdgcn_s_setprio(1);
    #pragma unroll
    for (int m = 0; m < 4; ++m)
      #pragma unroll
      for (int n = 0; n < 2; ++n)
        #pragma unroll
        for (int kk = 0; kk < 2; ++kk)
          acc[4 + m][2 + n] = __builtin_amdgcn_mfma_f32_16x16x32_bf16(a[m][kk], b1[n][kk], acc[4 + m][2 + n], 0, 0, 0);
    __builtin_amdgcn_s_setprio(0);
    BAR();

    // ---- P4: no reads; stage A0+A1(u+2) into this slot (dead since P3); gate; MFMA Q(m4-7,n0-1) ----
    if (nx2) { stageA(slot, u + 2, 0); stageA(slot, u + 2, 1); }
    if (nx2) { VMCNT(4); } else { VMCNT(0); }
    BAR();
    __builtin_amdgcn_s_setprio(1);
    #pragma unroll
    for (int m = 0; m < 4; ++m)
      #pragma unroll
      for (int n = 0; n < 2; ++n)
        #pragma unroll
        for (int kk = 0; kk < 2; ++kk)
          acc[4 + m][n] = __builtin_amdgcn_mfma_f32_16x16x32_bf16(a[m][kk], b0[n][kk], acc[4 + m][n], 0, 0, 0);
    __builtin_amdgcn_s_setprio(0);
    BAR();
  }

  // epilogue
  #pragma unroll
  for (int m = 0; m < 8; ++m) {
    #pragma unroll
    for (int n = 0; n < 4; ++n) {
      const int col = col0 + wn * 64 + n * 16 + lo;
      const float bb = bias[col];
      #pragma unroll
      for (int r = 0; r < 4; ++r) {
        const int row = row0 + wm * 128 + m * 16 + hi * 4 + r;
        C[(size_t)row * DMODEL + col] = f2bf(acc[m][n][r] + bb);
      }
    }
  }
}

// ---------------- out-proj NT GEMM: 128x64 tile, BK=32, 2-phase, 512 blocks ----------------
__global__ __launch_bounds__(256) void gemm_out64(
    const u16* __restrict__ A, const u16* __restrict__ Bt,
    const float* __restrict__ bias, float* __restrict__ C)
{
  constexpr int N = 1024, K = 1024;

  __shared__ u16 As[2][128 * 32];
  __shared__ u16 Bs[2][64 * 32];

  int id = blockIdx.y * gridDim.x + blockIdx.x;      // 0..511
  int wgid = (id & 7) * 64 + (id >> 3);
  const int row0 = (wgid >> 4) * 128;
  const int col0 = (wgid & 15) * 64;

  const int t = threadIdx.x;
  const int lane = t & 63, lo = lane & 15, hi = lane >> 4;
  const int wv = t >> 6;
  const int wr = (wv >> 1) * 64, wc = (wv & 1) * 32;

  f32x4 acc[4][2];
  #pragma unroll
  for (int i = 0; i < 4; ++i)
    #pragma unroll
    for (int j = 0; j < 2; ++j) acc[i][j] = (f32x4)0.0f;

  auto stage = [&](int buf, int kt) {
    const int kof = kt * 32;
    #pragma unroll
    for (int c = 0; c < 2; ++c) {
      const int off = t * 16 + c * 4096;
      const int r = off >> 6;
      const int ke = (off & 63) >> 1;
      GLDS16(A + (size_t)(row0 + r) * K + (kof + ke), (u16*)As + buf * (128 * 32) + (off >> 1));
    }
    {
      const int off = t * 16;
      const int r = off >> 6;
      const int ke = (off & 63) >> 1;
      GLDS16(Bt + (size_t)(col0 + r) * K + (kof + ke), (u16*)Bs + buf * (64 * 32) + (off >> 1));
    }
  };

  stage(0, 0);
  int cur = 0;
  for (int kt = 0; kt < (K >> 5); ++kt) {
    __syncthreads();
    if (kt + 1 < (K >> 5)) stage(cur ^ 1, kt + 1);
    bf16x8 af[4], bfr[2];
    #pragma unroll
    for (int mi = 0; mi < 4; ++mi)
      af[mi] = *(const bf16x8*)&As[cur][(wr + mi * 16 + lo) * 32 + hi * 8];
    #pragma unroll
    for (int ni = 0; ni < 2; ++ni)
      bfr[ni] = *(const bf16x8*)&Bs[cur][(wc + ni * 16 + lo) * 32 + hi * 8];
    #pragma unroll
    for (int mi = 0; mi < 4; ++mi)
      #pragma unroll
      for (int ni = 0; ni < 2; ++ni)
        acc[mi][ni] = __builtin_amdgcn_mfma_f32_16x16x32_bf16(af[mi], bfr[ni], acc[mi][ni], 0, 0, 0);
    cur ^= 1;
  }

  #pragma unroll
  for (int mi = 0; mi < 4; ++mi) {
    #pragma unroll
    for (int ni = 0; ni < 2; ++ni) {
      const int col = col0 + wc + ni * 16 + lo;
      const float bv = bias[col];
      #pragma unroll
      for (int r = 0; r < 4; ++r) {
        const int row = row0 + wr + mi * 16 + hi * 4 + r;
        C[(size_t)row * N + col] = acc[mi][ni][r] + bv;
      }
    }
  }
}

// ---------------- windowed causal attention: QBLK=128, 8 waves, static-max softmax ----------------
__device__ __forceinline__ int swzK(int row, int col) {   // K/P tiles
  int byte = (row << 7) + (col << 1);
  byte ^= (row & 7) << 4;
  return byte >> 1;
}
__device__ __forceinline__ int swzV(int d, int j) {       // Vt tile (row=d, col=j)
  int byte = (d << 7) + (j << 1);
  byte ^= ((d & 7) << 4) ^ (((d >> 4) & 3) << 5);
  return byte >> 1;
}

__global__ __launch_bounds__(512) void attn_win(const u16* __restrict__ Q,
                                                const u16* __restrict__ K,
                                                const u16* __restrict__ V,
                                                u16* __restrict__ O) {
  const int qt = blockIdx.x, h = blockIdx.y, b = blockIdx.z;
  const int q0 = qt * 128;
  const int t = threadIdx.x;
  const int wv = t >> 6, lane = t & 63, lo = lane & 15, hi = lane >> 4;

  __shared__ u16 Ks[2][64 * 64];
  __shared__ u16 Vt[2][64 * 64];
  __shared__ u16 Ps[8][16 * 64];

  const size_t base = ((size_t)b * S_LEN) * DMODEL + h * 64;
  const int w0 = q0 + wv * 16;          // this wave's 16-row strip

  // Q direct global->regs, pre-scaled by 1/8 (exact in bf16: exponent-only)
  bf16x8 qf[2];
  {
    const u16* qp = Q + base + (size_t)(w0 + lo) * DMODEL;
    u16x8 qa = *(const u16x8*)(qp + hi * 8);
    u16x8 qb = *(const u16x8*)(qp + 32 + hi * 8);
    union { u16x8 s; bf16x8 v; } ua, ub;
    #pragma unroll
    for (int e = 0; e < 8; ++e) {
      float fa = __builtin_bit_cast(float, (u32)qa[e] << 16) * 0.125f;
      float fb = __builtin_bit_cast(float, (u32)qb[e] << 16) * 0.125f;
      ua.s[e] = (u16)(__builtin_bit_cast(u32, fa) >> 16);   // exact
      ub.s[e] = (u16)(__builtin_bit_cast(u32, fb) >> 16);
    }
    qf[0] = ua.v; qf[1] = ub.v;
  }

  const int vrow = t >> 3;              // j in chunk (0..63)
  const int vc0  = (t & 7) * 8;         // d group (0..56)
  const int ktmin = max(0, (256 - q0) >> 6);

  u16x8 kra, vra;
  auto issue = [&](int kt) {
    const int jg = q0 - 256 + kt * 64 + vrow;
    if (jg >= 0) {
      kra = *(const u16x8*)(K + base + (size_t)jg * DMODEL + vc0);
      vra = *(const u16x8*)(V + base + (size_t)jg * DMODEL + vc0);
    } else { kra = (u16x8)0; vra = (u16x8)0; }
  };
  auto commit = [&](int buf) {
    *(u16x8*)&Ks[buf][swzK(vrow, vc0)] = kra;
    #pragma unroll
    for (int e = 0; e < 8; ++e)
      Vt[buf][swzV(vc0 + e, vrow)] = vra[e];
  };

  issue(ktmin);
  commit(0);
  __syncthreads();

  f32x4 oacc[4];
  #pragma unroll
  for (int i = 0; i < 4; ++i) oacc[i] = (f32x4)0.0f;
  float l_r[4] = {0.f, 0.f, 0.f, 0.f};

  int cur = 0;
  for (int kt = ktmin; kt < 6; ++kt) {
    const int kstart = q0 - 256 + kt * 64;
    if (kt < 5) issue(kt + 1);           // T14: next chunk's loads in flight

    const bool act = (kstart <= w0 + 15) && (kstart + 63 >= w0 - 255);
    if (act) {
      f32x4 sfr[4];
      #pragma unroll
      for (int ni = 0; ni < 4; ++ni) {
        sfr[ni] = (f32x4)0.0f;
        #pragma unroll
        for (int kq = 0; kq < 2; ++kq) {
          bf16x8 kf = *(const bf16x8*)&Ks[cur][swzK(ni * 16 + lo, kq * 32 + hi * 8)];
          sfr[ni] = __builtin_amdgcn_mfma_f32_16x16x32_bf16(qf[kq], kf, sfr[ni], 0, 0, 0);
        }
      }

      const int i0 = w0 + hi * 4;
      float pr[4][4];
      #pragma unroll
      for (int ni = 0; ni < 4; ++ni) {
        const int j = kstart + ni * 16 + lo;
        #pragma unroll
        for (int r = 0; r < 4; ++r) {
          const int i = i0 + r;
          const bool ok = (j >= 0) & (j <= i) & (i - j < WIN);
          const float x = ok ? sfr[ni][r] : -1e30f;
          const float p = __expf(x);     // exp(-1e30) == 0 -> masked entries vanish
          pr[ni][r] = p;
          l_r[r] += p;
        }
      }

      #pragma unroll
      for (int ni = 0; ni < 4; ++ni)
        #pragma unroll
        for (int r = 0; r < 4; ++r)
          Ps[wv][swzK(hi * 4 + r, ni * 16 + lo)] = f2bf(pr[ni][r]);

      bf16x8 pa[2];
      #pragma unroll
      for (int kp = 0; kp < 2; ++kp)
        pa[kp] = *(const bf16x8*)&Ps[wv][swzK(lo, kp * 32 + hi * 8)];

      #pragma unroll
      for (int ni = 0; ni < 4; ++ni) {
        #pragma unroll
        for (int kp = 0; kp < 2; ++kp) {
          bf16x8 vf = *(const bf16x8*)&Vt[cur][swzV(ni * 16 + lo, kp * 32 + hi * 8)];
          oacc[ni] = __builtin_amdgcn_mfma_f32_16x16x32_bf16(pa[kp], vf, oacc[ni], 0, 0, 0);
        }
      }
    }

    if (kt < 5) commit(cur ^ 1);         // vmcnt wait lands here, writes buf^1
    __syncthreads();                      // one barrier per chunk
    cur ^= 1;
  }

  #pragma unroll
  for (int d = 1; d < 16; d <<= 1) {
    #pragma unroll
    for (int r = 0; r < 4; ++r) l_r[r] += __shfl_xor(l_r[r], d);
  }

  #pragma unroll
  for (int r = 0; r < 4; ++r) {
    const float inv = 1.0f / l_r[r];
    const int row = w0 + hi * 4 + r;
    #pragma unroll
    for (int ni = 0; ni < 4; ++ni)
      O[base + (size_t)row * DMODEL + ni * 16 + lo] = f2bf(oacc[ni][r] * inv);
  }
}

// ---------------- launch ----------------
extern "C" void kernel_launch(void* const* d_in, const int* in_sizes, int n_in,
                              void* d_out, int out_size, void* d_ws, size_t ws_size,
                              hipStream_t stream) {
  const float* x  = (const float*)d_in[0];
  const float* wq = (const float*)d_in[1];
  const float* bq = (const float*)d_in[2];
  const float* wk = (const float*)d_in[3];
  const float* bk = (const float*)d_in[4];
  const float* wvp = (const float*)d_in[5];
  const float* bv = (const float*)d_in[6];
  const float* wo = (const float*)d_in[7];
  const float* bo = (const float*)d_in[8];
  float* out = (float*)d_out;

  char* ws = (char*)d_ws;
  const size_t MB = 1024 * 1024;
  u16* xb  = (u16*)(ws);
  u16* wqb = (u16*)(ws + 8 * MB);
  u16* wkb = (u16*)(ws + 10 * MB);
  u16* wvb = (u16*)(ws + 12 * MB);
  u16* wob = (u16*)(ws + 14 * MB);
  u16* Qb  = (u16*)(ws + 16 * MB);
  u16* Kb  = (u16*)(ws + 24 * MB);
  u16* Vb  = (u16*)(ws + 32 * MB);
  u16* Ob  = (u16*)(ws + 40 * MB);   // ends at 48 MB

  cast_all<<<8192, 256, 0, stream>>>(x, wq, wk, wvp, wo, xb, wqb, wkb, wvb, wob);

  gemm_qkv_8ph<<<dim3(16, 12), 512, 0, stream>>>(xb, wqb, wkb, wvb, bq, bk, bv, Qb, Kb, Vb);

  attn_win<<<dim3(S_LEN / 128, NHEADS, 2), 512, 0, stream>>>(Qb, Kb, Vb, Ob);

  gemm_out64<<<dim3(32, 16), 256, 0, stream>>>(Ob, wob, bo, out);
}

// Round 9
// 81.425 us; speedup vs baseline: 1.0779x; 1.0779x over previous
//
#include <hip/hip_runtime.h>

#define S_LEN 2048
#define DMODEL 1024
#define NHEADS 16
#define WIN 256

typedef unsigned short u16;
typedef unsigned int u32;
typedef __attribute__((ext_vector_type(8))) __bf16 bf16x8;
typedef __attribute__((ext_vector_type(4))) float f32x4;
typedef __attribute__((ext_vector_type(8))) u16 u16x8;
typedef __attribute__((ext_vector_type(4))) u16 u16x4;

__device__ __forceinline__ u16 f2bf(float f) {
  u32 u = __builtin_bit_cast(u32, f);
  u += 0x7fffu + ((u >> 16) & 1u);   // round-to-nearest-even
  return (u16)(u >> 16);
}

#define GLDS16(g, l) __builtin_amdgcn_global_load_lds( \
    (const __attribute__((address_space(1))) void*)(g), \
    (__attribute__((address_space(3))) void*)(l), 16, 0, 0)

#define BAR() { asm volatile("" ::: "memory"); __builtin_amdgcn_s_barrier(); asm volatile("" ::: "memory"); }
#define VMCNT(n) asm volatile("s_waitcnt vmcnt(" #n ")" ::: "memory")

// ---------------- fused cast f32 -> bf16 (x + 4 weights, one launch) ----------------
__global__ __launch_bounds__(256) void cast_all(
    const float* __restrict__ x, const float* __restrict__ wq, const float* __restrict__ wk,
    const float* __restrict__ wv, const float* __restrict__ wo,
    u16* __restrict__ xb, u16* __restrict__ wqb, u16* __restrict__ wkb,
    u16* __restrict__ wvb, u16* __restrict__ wob) {
  const int e = (blockIdx.x * 256 + threadIdx.x) * 4;
  const float* src; u16* dst; int off;
  if (e < (1 << 22)) { src = x; dst = xb; off = e; }
  else {
    int r = e - (1 << 22);
    int seg = r >> 20; off = r & ((1 << 20) - 1);
    src = (seg == 0) ? wq : (seg == 1) ? wk : (seg == 2) ? wv : wo;
    dst = (seg == 0) ? wqb : (seg == 1) ? wkb : (seg == 2) ? wvb : wob;
  }
  float4 v = *(const float4*)(src + off);
  u16x4 o = { f2bf(v.x), f2bf(v.y), f2bf(v.z), f2bf(v.w) };
  *(u16x4*)(dst + off) = o;
}

// ---------------- NT GEMM (QKV): 128x128, BK=32, counted-vmcnt 2-phase + T2(BK32) ----------------
// Schedule per K-tile: VMCNT(4) [tile kt's 4 loads of 8 outstanding] -> BAR ->
// swizzled ds_read + 16 MFMA -> BAR -> stage tile kt+2 into freed buffer.
// T2: LDS 16B-slot ^= (row&3); realized as inverse-swizzled global src (linear
// global_load_lds dest) + swizzled read. 8-way -> 4-way read bank conflict.
__global__ __launch_bounds__(256) void gemm_nt(
    const u16* __restrict__ A,
    const u16* __restrict__ B0, const u16* __restrict__ B1, const u16* __restrict__ B2,
    const float* __restrict__ bias0, const float* __restrict__ bias1, const float* __restrict__ bias2,
    u16* __restrict__ C0, u16* __restrict__ C1, u16* __restrict__ C2,
    const int M, const int N, const int K)
{
  const u16* Bt; const float* bias; u16* C;
  if (blockIdx.z == 0)      { Bt = B0; bias = bias0; C = C0; }
  else if (blockIdx.z == 1) { Bt = B1; bias = bias1; C = C1; }
  else                      { Bt = B2; bias = bias2; C = C2; }

  __shared__ u16 As[2][128 * 32];
  __shared__ u16 Bs[2][128 * 32];

  const int t = threadIdx.x;
  const int row0 = blockIdx.x * 128;
  const int col0 = blockIdx.y * 128;
  const int lane = t & 63, lo = lane & 15, hi = lane >> 4;
  const int wv = t >> 6;
  const int wr = (wv >> 1) * 64, wc = (wv & 1) * 64;
  const int sx = lo & 3;                      // row&3 of every fragment row this lane reads

  f32x4 acc[4][4];
  #pragma unroll
  for (int i = 0; i < 4; ++i)
    #pragma unroll
    for (int j = 0; j < 4; ++j) acc[i][j] = (f32x4)0.0f;

  const int NT = K >> 5;

  // staging decode (per thread, loop-invariant): linear LDS byte off = t*16 + c*4096
  //   r = off>>6 (row), slot = (off>>4)&3; source k16-group = slot ^ (r&3)
  auto stage = [&](int buf, int kt) {
    const int kof = kt * 32;
    #pragma unroll
    for (int c = 0; c < 2; ++c) {
      const int off = t * 16 + c * 4096;
      const int r = off >> 6;
      const int g = ((off >> 4) & 3) ^ (r & 3);
      GLDS16(A  + (size_t)(row0 + r) * K + (kof + g * 8), (u16*)As + buf * 4096 + (off >> 1));
      GLDS16(Bt + (size_t)(col0 + r) * K + (kof + g * 8), (u16*)Bs + buf * 4096 + (off >> 1));
    }
  };

  stage(0, 0);
  stage(1, 1);                                // 8 loads in flight
  for (int kt = 0; kt < NT; ++kt) {
    const int cur = kt & 1;
    if (kt + 1 < NT) { VMCNT(4); } else { VMCNT(0); }
    BAR();                                    // tile kt fully staged (all waves gated)
    bf16x8 af[4], bfr[4];
    #pragma unroll
    for (int mi = 0; mi < 4; ++mi) {
      const int row = wr + mi * 16 + lo;
      af[mi] = *(const bf16x8*)&As[cur][row * 32 + ((hi ^ sx) << 3)];
    }
    #pragma unroll
    for (int ni = 0; ni < 4; ++ni) {
      const int row = wc + ni * 16 + lo;
      bfr[ni] = *(const bf16x8*)&Bs[cur][row * 32 + ((hi ^ sx) << 3)];
    }
    #pragma unroll
    for (int mi = 0; mi < 4; ++mi)
      #pragma unroll
      for (int ni = 0; ni < 4; ++ni)
        acc[mi][ni] = __builtin_amdgcn_mfma_f32_16x16x32_bf16(af[mi], bfr[ni], acc[mi][ni], 0, 0, 0);
    BAR();                                    // all waves done reading buf[cur]
    if (kt + 2 < NT) stage(cur, kt + 2);      // restage freed buffer; loads span next iter
  }

  #pragma unroll
  for (int mi = 0; mi < 4; ++mi) {
    #pragma unroll
    for (int ni = 0; ni < 4; ++ni) {
      const int col = col0 + wc + ni * 16 + lo;
      const float bv = bias[col];
      #pragma unroll
      for (int r = 0; r < 4; ++r) {
        const int row = row0 + wr + mi * 16 + hi * 4 + r;
        C[(size_t)row * N + col] = f2bf(acc[mi][ni][r] + bv);
      }
    }
  }
}

// ---------------- out-proj NT GEMM: 128x64, BK=32, counted-vmcnt 2-phase + T2(BK32) ----------------
__global__ __launch_bounds__(256) void gemm_out64(
    const u16* __restrict__ A, const u16* __restrict__ Bt,
    const float* __restrict__ bias, float* __restrict__ C)
{
  constexpr int N = 1024, K = 1024;

  __shared__ u16 As[2][128 * 32];
  __shared__ u16 Bs[2][64 * 32];

  int id = blockIdx.y * gridDim.x + blockIdx.x;      // 0..511
  int wgid = (id & 7) * 64 + (id >> 3);
  const int row0 = (wgid >> 4) * 128;
  const int col0 = (wgid & 15) * 64;

  const int t = threadIdx.x;
  const int lane = t & 63, lo = lane & 15, hi = lane >> 4;
  const int wv = t >> 6;
  const int wr = (wv >> 1) * 64, wc = (wv & 1) * 32;
  const int sx = lo & 3;

  f32x4 acc[4][2];
  #pragma unroll
  for (int i = 0; i < 4; ++i)
    #pragma unroll
    for (int j = 0; j < 2; ++j) acc[i][j] = (f32x4)0.0f;

  auto stage = [&](int buf, int kt) {
    const int kof = kt * 32;
    #pragma unroll
    for (int c = 0; c < 2; ++c) {              // A: 128x32 = 2 rounds
      const int off = t * 16 + c * 4096;
      const int r = off >> 6;
      const int g = ((off >> 4) & 3) ^ (r & 3);
      GLDS16(A + (size_t)(row0 + r) * K + (kof + g * 8), (u16*)As + buf * 4096 + (off >> 1));
    }
    {                                           // B: 64x32 = 1 round
      const int off = t * 16;
      const int r = off >> 6;
      const int g = ((off >> 4) & 3) ^ (r & 3);
      GLDS16(Bt + (size_t)(col0 + r) * K + (kof + g * 8), (u16*)Bs + buf * 2048 + (off >> 1));
    }
  };

  stage(0, 0);
  stage(1, 1);                                  // 6 loads in flight
  for (int kt = 0; kt < (K >> 5); ++kt) {
    const int cur = kt & 1;
    if (kt + 1 < (K >> 5)) { VMCNT(3); } else { VMCNT(0); }
    BAR();
    bf16x8 af[4], bfr[2];
    #pragma unroll
    for (int mi = 0; mi < 4; ++mi) {
      const int row = wr + mi * 16 + lo;
      af[mi] = *(const bf16x8*)&As[cur][row * 32 + ((hi ^ sx) << 3)];
    }
    #pragma unroll
    for (int ni = 0; ni < 2; ++ni) {
      const int row = wc + ni * 16 + lo;
      bfr[ni] = *(const bf16x8*)&Bs[cur][row * 32 + ((hi ^ sx) << 3)];
    }
    #pragma unroll
    for (int mi = 0; mi < 4; ++mi)
      #pragma unroll
      for (int ni = 0; ni < 2; ++ni)
        acc[mi][ni] = __builtin_amdgcn_mfma_f32_16x16x32_bf16(af[mi], bfr[ni], acc[mi][ni], 0, 0, 0);
    BAR();
    if (kt + 2 < (K >> 5)) stage(cur, kt + 2);
  }

  #pragma unroll
  for (int mi = 0; mi < 4; ++mi) {
    #pragma unroll
    for (int ni = 0; ni < 2; ++ni) {
      const int col = col0 + wc + ni * 16 + lo;
      const float bv = bias[col];
      #pragma unroll
      for (int r = 0; r < 4; ++r) {
        const int row = row0 + wr + mi * 16 + hi * 4 + r;
        C[(size_t)row * N + col] = acc[mi][ni][r] + bv;
      }
    }
  }
}

// ---------------- windowed causal attention: QBLK=128, 8 waves, static-max softmax ----------------
__device__ __forceinline__ int swzK(int row, int col) {   // K/P tiles
  int byte = (row << 7) + (col << 1);
  byte ^= (row & 7) << 4;
  return byte >> 1;
}
__device__ __forceinline__ int swzV(int d, int j) {       // Vt tile (row=d, col=j)
  int byte = (d << 7) + (j << 1);
  byte ^= ((d & 7) << 4) ^ (((d >> 4) & 3) << 5);
  return byte >> 1;
}

__global__ __launch_bounds__(512) void attn_win(const u16* __restrict__ Q,
                                                const u16* __restrict__ K,
                                                const u16* __restrict__ V,
                                                u16* __restrict__ O) {
  const int qt = blockIdx.x, h = blockIdx.y, b = blockIdx.z;
  const int q0 = qt * 128;
  const int t = threadIdx.x;
  const int wv = t >> 6, lane = t & 63, lo = lane & 15, hi = lane >> 4;

  __shared__ u16 Ks[2][64 * 64];
  __shared__ u16 Vt[2][64 * 64];
  __shared__ u16 Ps[8][16 * 64];

  const size_t base = ((size_t)b * S_LEN) * DMODEL + h * 64;
  const int w0 = q0 + wv * 16;          // this wave's 16-row strip

  // Q direct global->regs, pre-scaled by 1/8 (exact in bf16: exponent-only)
  bf16x8 qf[2];
  {
    const u16* qp = Q + base + (size_t)(w0 + lo) * DMODEL;
    u16x8 qa = *(const u16x8*)(qp + hi * 8);
    u16x8 qb = *(const u16x8*)(qp + 32 + hi * 8);
    union { u16x8 s; bf16x8 v; } ua, ub;
    #pragma unroll
    for (int e = 0; e < 8; ++e) {
      float fa = __builtin_bit_cast(float, (u32)qa[e] << 16) * 0.125f;
      float fb = __builtin_bit_cast(float, (u32)qb[e] << 16) * 0.125f;
      ua.s[e] = (u16)(__builtin_bit_cast(u32, fa) >> 16);   // exact
      ub.s[e] = (u16)(__builtin_bit_cast(u32, fb) >> 16);
    }
    qf[0] = ua.v; qf[1] = ub.v;
  }

  const int vrow = t >> 3;              // j in chunk (0..63)
  const int vc0  = (t & 7) * 8;         // d group (0..56)
  const int ktmin = max(0, (256 - q0) >> 6);

  u16x8 kra, vra;
  auto issue = [&](int kt) {
    const int jg = q0 - 256 + kt * 64 + vrow;
    if (jg >= 0) {
      kra = *(const u16x8*)(K + base + (size_t)jg * DMODEL + vc0);
      vra = *(const u16x8*)(V + base + (size_t)jg * DMODEL + vc0);
    } else { kra = (u16x8)0; vra = (u16x8)0; }
  };
  auto commit = [&](int buf) {
    *(u16x8*)&Ks[buf][swzK(vrow, vc0)] = kra;
    #pragma unroll
    for (int e = 0; e < 8; ++e)
      Vt[buf][swzV(vc0 + e, vrow)] = vra[e];
  };

  issue(ktmin);
  commit(0);
  __syncthreads();

  f32x4 oacc[4];
  #pragma unroll
  for (int i = 0; i < 4; ++i) oacc[i] = (f32x4)0.0f;
  float l_r[4] = {0.f, 0.f, 0.f, 0.f};

  int cur = 0;
  for (int kt = ktmin; kt < 6; ++kt) {
    const int kstart = q0 - 256 + kt * 64;
    if (kt < 5) issue(kt + 1);           // T14: next chunk's loads in flight

    const bool act = (kstart <= w0 + 15) && (kstart + 63 >= w0 - 255);
    if (act) {
      f32x4 sfr[4];
      #pragma unroll
      for (int ni = 0; ni < 4; ++ni) {
        sfr[ni] = (f32x4)0.0f;
        #pragma unroll
        for (int kq = 0; kq < 2; ++kq) {
          bf16x8 kf = *(const bf16x8*)&Ks[cur][swzK(ni * 16 + lo, kq * 32 + hi * 8)];
          sfr[ni] = __builtin_amdgcn_mfma_f32_16x16x32_bf16(qf[kq], kf, sfr[ni], 0, 0, 0);
        }
      }

      const int i0 = w0 + hi * 4;
      float pr[4][4];
      #pragma unroll
      for (int ni = 0; ni < 4; ++ni) {
        const int j = kstart + ni * 16 + lo;
        #pragma unroll
        for (int r = 0; r < 4; ++r) {
          const int i = i0 + r;
          const bool ok = (j >= 0) & (j <= i) & (i - j < WIN);
          const float x = ok ? sfr[ni][r] : -1e30f;
          const float p = __expf(x);     // exp(-1e30) == 0 -> masked entries vanish
          pr[ni][r] = p;
          l_r[r] += p;
        }
      }

      #pragma unroll
      for (int ni = 0; ni < 4; ++ni)
        #pragma unroll
        for (int r = 0; r < 4; ++r)
          Ps[wv][swzK(hi * 4 + r, ni * 16 + lo)] = f2bf(pr[ni][r]);

      bf16x8 pa[2];
      #pragma unroll
      for (int kp = 0; kp < 2; ++kp)
        pa[kp] = *(const bf16x8*)&Ps[wv][swzK(lo, kp * 32 + hi * 8)];

      #pragma unroll
      for (int ni = 0; ni < 4; ++ni) {
        #pragma unroll
        for (int kp = 0; kp < 2; ++kp) {
          bf16x8 vf = *(const bf16x8*)&Vt[cur][swzV(ni * 16 + lo, kp * 32 + hi * 8)];
          oacc[ni] = __builtin_amdgcn_mfma_f32_16x16x32_bf16(pa[kp], vf, oacc[ni], 0, 0, 0);
        }
      }
    }

    if (kt < 5) commit(cur ^ 1);         // vmcnt wait lands here, writes buf^1
    __syncthreads();                      // one barrier per chunk
    cur ^= 1;
  }

  #pragma unroll
  for (int d = 1; d < 16; d <<= 1) {
    #pragma unroll
    for (int r = 0; r < 4; ++r) l_r[r] += __shfl_xor(l_r[r], d);
  }

  #pragma unroll
  for (int r = 0; r < 4; ++r) {
    const float inv = 1.0f / l_r[r];
    const int row = w0 + hi * 4 + r;
    #pragma unroll
    for (int ni = 0; ni < 4; ++ni)
      O[base + (size_t)row * DMODEL + ni * 16 + lo] = f2bf(oacc[ni][r] * inv);
  }
}

// ---------------- launch ----------------
extern "C" void kernel_launch(void* const* d_in, const int* in_sizes, int n_in,
                              void* d_out, int out_size, void* d_ws, size_t ws_size,
                              hipStream_t stream) {
  const float* x  = (const float*)d_in[0];
  const float* wq = (const float*)d_in[1];
  const float* bq = (const float*)d_in[2];
  const float* wk = (const float*)d_in[3];
  const float* bk = (const float*)d_in[4];
  const float* wvp = (const float*)d_in[5];
  const float* bv = (const float*)d_in[6];
  const float* wo = (const float*)d_in[7];
  const float* bo = (const float*)d_in[8];
  float* out = (float*)d_out;

  char* ws = (char*)d_ws;
  const size_t MB = 1024 * 1024;
  u16* xb  = (u16*)(ws);
  u16* wqb = (u16*)(ws + 8 * MB);
  u16* wkb = (u16*)(ws + 10 * MB);
  u16* wvb = (u16*)(ws + 12 * MB);
  u16* wob = (u16*)(ws + 14 * MB);
  u16* Qb  = (u16*)(ws + 16 * MB);
  u16* Kb  = (u16*)(ws + 24 * MB);
  u16* Vb  = (u16*)(ws + 32 * MB);
  u16* Ob  = (u16*)(ws + 40 * MB);   // ends at 48 MB

  cast_all<<<8192, 256, 0, stream>>>(x, wq, wk, wvp, wo, xb, wqb, wkb, wvb, wob);

  dim3 g1(4096 / 128, 1024 / 128, 3);
  gemm_nt<<<g1, 256, 0, stream>>>(xb, wqb, wkb, wvb, bq, bk, bv,
                                  Qb, Kb, Vb, 4096, 1024, 1024);

  attn_win<<<dim3(S_LEN / 128, NHEADS, 2), 512, 0, stream>>>(Qb, Kb, Vb, Ob);

  gemm_out64<<<dim3(32, 16), 256, 0, stream>>>(Ob, wob, bo, out);
}